// Round 7
// baseline (526.305 us; speedup 1.0000x reference)
//
#include <hip/hip_runtime.h>

// Problem constants
#define B_    2
#define T_    2048
#define HID_  2048
#define NH_   32
#define NKV_  8
#define HD_   64
#define STEPS_ 2
#define SCALE_ 0.125f
// SCALE * log2(e): scores kept in exp2 domain throughout (folded into q at RoPE)
#define CSC_  0.18033688011112042f

typedef float   f32x4  __attribute__((ext_vector_type(4)));
typedef __bf16  bf16x8 __attribute__((ext_vector_type(8)));
typedef unsigned short u16x8 __attribute__((ext_vector_type(8)));

__device__ __forceinline__ unsigned short f2bf(float f) {
  unsigned int u = __builtin_bit_cast(unsigned int, f);
  u = (u + 0x7fffu + ((u >> 16) & 1u)) >> 16;
  return (unsigned short)u;
}
__device__ __forceinline__ float bf2f(unsigned short h) {
  unsigned int u = ((unsigned int)h) << 16;
  return __builtin_bit_cast(float, u);
}
__device__ __forceinline__ bf16x8 frag_ld(const unsigned short* p) {
  u16x8 v = *(const u16x8*)p;
  return __builtin_bit_cast(bf16x8, v);
}
__device__ __forceinline__ f32x4 mfma16(bf16x8 a, bf16x8 b, f32x4 c) {
  return __builtin_amdgcn_mfma_f32_16x16x32_bf16(a, b, c, 0, 0, 0);
}
__device__ __forceinline__ void async_cp16(const void* g, void* l) {
  __builtin_amdgcn_global_load_lds(
      (const __attribute__((address_space(1))) void*)g,
      (__attribute__((address_space(3))) void*)l, 16, 0, 0);
}
// HW packed f32->bf16 (RNE), no builtin on gfx950 -> inline asm (guide T12)
__device__ __forceinline__ unsigned int cvtpk_bf16(float lo, float hi) {
  unsigned int r;
  asm("v_cvt_pk_bf16_f32 %0, %1, %2" : "=v"(r) : "v"(lo), "v"(hi));
  return r;
}

// ---------------------------------------------------------------------------
// elementwise fp32 -> bf16 convert (float4 per thread)
__global__ __launch_bounds__(256) void convert_bf16(const float* __restrict__ in,
                                                    unsigned short* __restrict__ out,
                                                    int n4) {
  int idx = blockIdx.x * 256 + threadIdx.x;
  if (idx < n4) {
    float4 v = ((const float4*)in)[idx];
    ushort4 o;
    o.x = f2bf(v.x); o.y = f2bf(v.y); o.z = f2bf(v.z); o.w = f2bf(v.w);
    ((ushort4*)out)[idx] = o;
  }
}

// merged Wq/Wk/Wv transpose+convert into WqkvT [3072][4096]
//  bx 0..31 -> Wq (4096x2048), 32..39 -> Wk (4096x512), 40..47 -> Wv
__global__ __launch_bounds__(256) void transpose_wqkv(const float* __restrict__ Wq,
                                                      const float* __restrict__ Wk,
                                                      const float* __restrict__ Wv,
                                                      unsigned short* __restrict__ out) {
  __shared__ float tile[64][65];
  int bx = blockIdx.x;
  const float* in; int N; int nbase;
  if (bx < 32)      { in = Wq; N = 2048; nbase = 0;    }
  else if (bx < 40) { in = Wk; N = 512;  nbase = 2048; bx -= 32; }
  else              { in = Wv; N = 512;  nbase = 2560; bx -= 40; }
  int n0 = bx * 64, k0 = blockIdx.y * 64;
  int c = threadIdx.x & 63, w = threadIdx.x >> 6;
#pragma unroll
  for (int i = 0; i < 16; i++) {
    int r = w * 16 + i;
    tile[r][c] = in[(size_t)(k0 + r) * N + n0 + c];
  }
  __syncthreads();
#pragma unroll
  for (int i = 0; i < 16; i++) {
    int rr = w * 16 + i;
    out[(size_t)(nbase + n0 + rr) * 4096 + k0 + c] = f2bf(tile[c][rr]);
  }
}

// transpose + convert: in (K x N fp32 row-major) -> out (N x K bf16, ld=ldo)
__global__ __launch_bounds__(256) void transpose_f32_bf16_ld(const float* __restrict__ in,
                                                             unsigned short* __restrict__ out,
                                                             int K, int N, int ldo) {
  __shared__ float tile[64][65];
  int n0 = blockIdx.x * 64, k0 = blockIdx.y * 64;
  int c = threadIdx.x & 63, w = threadIdx.x >> 6;
#pragma unroll
  for (int i = 0; i < 16; i++) {
    int r = w * 16 + i;
    tile[r][c] = in[(size_t)(k0 + r) * N + n0 + c];
  }
  __syncthreads();
#pragma unroll
  for (int i = 0; i < 16; i++) {
    int rr = w * 16 + i;
    out[(size_t)(n0 + rr) * ldo + k0 + c] = f2bf(tile[c][rr]);
  }
}

// v0 (B*NH slabs of [T][D] fp32) -> v0t bf16 [B*NH][D][T]
__global__ __launch_bounds__(256) void transpose_v0(const float* __restrict__ v0,
                                                    unsigned short* __restrict__ v0t) {
  __shared__ float tile[64][65];
  int s0 = blockIdx.x * 64;
  int bh = blockIdx.y;
  const float* src = v0 + (size_t)bh * T_ * HD_;
  unsigned short* dst = v0t + (size_t)bh * HD_ * T_;
  int c = threadIdx.x & 63, w = threadIdx.x >> 6;
#pragma unroll
  for (int i = 0; i < 16; i++) {
    int r = w * 16 + i;
    tile[r][c] = src[(size_t)(s0 + r) * HD_ + c];
  }
  __syncthreads();
#pragma unroll
  for (int i = 0; i < 16; i++) {
    int rr = w * 16 + i;
    dst[(size_t)rr * T_ + s0 + c] = f2bf(tile[c][rr]);
  }
}

// ---------------------------------------------------------------------------
// 128 x (NF*64) 8-phase bf16 GEMM: C(MxN fp32) = A(MxK) * Bt(NxK)^T
// (schedule/ledger unchanged from round 4 -- verified)
// NEW: bijective XCD-aware block swizzle (requires gridDim.x == 32, grid 256):
//  nl = (lid&7)*32 + (lid>>3)  -> each XCD owns one N-panel (L2-resident B)
//  and streams A (L3-resident).
// ---------------------------------------------------------------------------
#define SBAR  do { __builtin_amdgcn_sched_barrier(0); __builtin_amdgcn_s_barrier(); \
                   __builtin_amdgcn_sched_barrier(0); } while (0)
#define LGKM0 do { asm volatile("s_waitcnt lgkmcnt(0)" ::: "memory"); \
                   __builtin_amdgcn_sched_barrier(0); } while (0)
#define VM2   do { asm volatile("s_waitcnt vmcnt(2)" ::: "memory"); } while (0)
#define VM0   do { asm volatile("s_waitcnt vmcnt(0)" ::: "memory"); } while (0)

template <int NF>
__global__ __launch_bounds__(512, 2) void gemm128_bt(const unsigned short* __restrict__ A,
                                                     const unsigned short* __restrict__ Bt,
                                                     float* __restrict__ C,
                                                     int M, int N, int K) {
  constexpr int NHF = NF / 2;             // B frags per qn group per wave
  constexpr int BROWS = 128 + NF * 64;    // rows staged per buffer
  __shared__ __attribute__((aligned(128))) unsigned short smem[2][BROWS * 64];

  const int tid  = threadIdx.x;
  const int lane = tid & 63;
  const int wid  = tid >> 6;      // 0..7
  const int wr   = wid >> 2;      // 0..1  (M half: 64 rows)
  const int wc   = wid & 3;       // 0..3  (N quarter: NF*16 cols)
  const int la   = lane & 15;
  const int lq   = lane >> 4;
  const int sw   = la & 7;        // read-side swizzle key (row&7 == la&7)

  // XCD-aware bijective swizzle (gridDim.x==32, 256 blocks, 8 XCDs)
  const int lid = blockIdx.x + blockIdx.y * 32;
  const int nl  = (lid & 7) * 32 + (lid >> 3);
  const int m0  = (nl & 31) * 128;
  const int n0  = (nl >> 5) * (NF * 64);

  // staging: chunk = wid*2+is (1 KiB, 8 rows); lane covers physical
  // (row = chunk*8 + (lane>>3), slot = lane&7); fetches logical slot
  // (lane&7)^(row&7) so the linear DMA image realizes the XOR swizzle.
  const int sr = lane >> 3;
  const int sl = (lane & 7) ^ sr;

  const unsigned short* gA[2];
  const unsigned short* gB[NHF][2];
#pragma unroll
  for (int is = 0; is < 2; ++is) {
    int r = (wid * 2 + is) * 8 + sr;
    gA[is] = A + (size_t)(m0 + r) * K + sl * 8;
#pragma unroll
    for (int u = 0; u < NHF; ++u)
      gB[u][is] = Bt + (size_t)(n0 + u * 128 + r) * K + sl * 8;
  }

#define G_STG_A(buf, kt) do { \
    async_cp16(gA[0] + (size_t)(kt) * 64, &smem[buf][(wid * 2 + 0) * 512]); \
    async_cp16(gA[1] + (size_t)(kt) * 64, &smem[buf][(wid * 2 + 1) * 512]); \
  } while (0)
#define G_STG_B(buf, u, kt) do { \
    async_cp16(gB[u][0] + (size_t)(kt) * 64, &smem[buf][(128 + (u) * 128) * 64 + (wid * 2 + 0) * 512]); \
    async_cp16(gB[u][1] + (size_t)(kt) * 64, &smem[buf][(128 + (u) * 128) * 64 + (wid * 2 + 1) * 512]); \
  } while (0)

  f32x4  acc[4][NF] = {};
  bf16x8 aR[2][2], b0r[NHF][2], b1r[NHF][2];

#define G_RD_A(buf, qm) do { \
    const unsigned short* rp_ = &smem[buf][0]; \
    _Pragma("unroll") \
    for (int i_ = 0; i_ < 2; ++i_) { \
      int ro_ = (wr * 64 + (qm) * 32 + i_ * 16 + la) * 64; \
      aR[i_][0] = frag_ld(rp_ + ro_ + (((0 + lq) ^ sw) << 3)); \
      aR[i_][1] = frag_ld(rp_ + ro_ + (((4 + lq) ^ sw) << 3)); \
    } \
  } while (0)
#define G_RD_B(buf, qn, breg) do { \
    const unsigned short* rp_ = &smem[buf][128 * 64]; \
    _Pragma("unroll") \
    for (int j_ = 0; j_ < NHF; ++j_) { \
      int ro_ = (wc * (NF * 16) + (qn) * (NF * 8) + j_ * 16 + la) * 64; \
      breg[j_][0] = frag_ld(rp_ + ro_ + (((0 + lq) ^ sw) << 3)); \
      breg[j_][1] = frag_ld(rp_ + ro_ + (((4 + lq) ^ sw) << 3)); \
    } \
  } while (0)
#define G_MMA(qm, qn, breg) do { \
    _Pragma("unroll") \
    for (int i_ = 0; i_ < 2; ++i_) \
      _Pragma("unroll") \
      for (int j_ = 0; j_ < NHF; ++j_) { \
        f32x4 c_ = acc[(qm) * 2 + i_][(qn) * NHF + j_]; \
        c_ = mfma16(aR[i_][0], breg[j_][0], c_); \
        c_ = mfma16(aR[i_][1], breg[j_][1], c_); \
        acc[(qm) * 2 + i_][(qn) * NHF + j_] = c_; \
      } \
  } while (0)

  // prologue: tile0 fully -> buf0; tile1's prev-P8-role slot -> buf1.
  G_STG_A(0, 0);
#pragma unroll
  for (int u = 0; u < NHF; ++u) G_STG_B(0, u, 0);
  if constexpr (NF == 6) G_STG_B(1, 2, 1); else G_STG_A(1, 1);
  VM2;   // tile0's slots landed; the buf1 slot may stay in flight
  SBAR;

  const int NI = K >> 7;   // iterations of 2 K-tiles (K multiple of 128)
  for (int it = 0; it < NI; ++it) {
    const int e = it * 2;
    const bool pf = (it + 1 < NI);
    // ---- P1
    G_RD_A(0, 0);
    G_RD_B(0, 0, b0r);
    if constexpr (NF == 6) G_STG_A(1, e + 1); else G_STG_B(1, 0, e + 1);
    SBAR; LGKM0;
    __builtin_amdgcn_s_setprio(1); G_MMA(0, 0, b0r); __builtin_amdgcn_s_setprio(0);
    SBAR;
    // ---- P2
    G_RD_B(0, 1, b1r);
    if constexpr (NF == 6) G_STG_B(1, 0, e + 1); else G_STG_B(1, 1, e + 1);
    SBAR; LGKM0;
    __builtin_amdgcn_s_setprio(1); G_MMA(0, 1, b1r); __builtin_amdgcn_s_setprio(0);
    SBAR;
    // ---- P3
    G_RD_A(0, 1);
    if constexpr (NF == 6) G_STG_B(1, 1, e + 1);
    SBAR; LGKM0;
    __builtin_amdgcn_s_setprio(1); G_MMA(1, 1, b1r); __builtin_amdgcn_s_setprio(0);
    SBAR;
    // ---- P4
    if (pf) G_STG_A(0, e + 2);
    SBAR; LGKM0;
    __builtin_amdgcn_s_setprio(1); G_MMA(1, 0, b0r); __builtin_amdgcn_s_setprio(0);
    if (pf) { VM2; } else { VM0; }
    SBAR;
    // ---- P5
    G_RD_A(1, 0);
    G_RD_B(1, 0, b0r);
    if (pf) G_STG_B(0, 0, e + 2);
    SBAR; LGKM0;
    __builtin_amdgcn_s_setprio(1); G_MMA(0, 0, b0r); __builtin_amdgcn_s_setprio(0);
    SBAR;
    // ---- P6
    G_RD_B(1, 1, b1r);
    if (pf) G_STG_B(0, 1, e + 2);
    SBAR; LGKM0;
    __builtin_amdgcn_s_setprio(1); G_MMA(0, 1, b1r); __builtin_amdgcn_s_setprio(0);
    SBAR;
    // ---- P7
    G_RD_A(1, 1);
    if constexpr (NF == 6) { if (pf) G_STG_B(0, 2, e + 2); }
    SBAR; LGKM0;
    __builtin_amdgcn_s_setprio(1); G_MMA(1, 1, b1r); __builtin_amdgcn_s_setprio(0);
    SBAR;
    // ---- P8
    if constexpr (NF == 6) { if (pf) G_STG_B(1, 2, e + 3); }
    else                   { if (pf) G_STG_A(1, e + 3); }
    SBAR; LGKM0;
    __builtin_amdgcn_s_setprio(1); G_MMA(1, 0, b0r); __builtin_amdgcn_s_setprio(0);
    VM2;
    SBAR;
  }

  // epilogue: C[row, col], col = frag col + la, row = lq*4 + r within frag
#pragma unroll
  for (int mf = 0; mf < 4; ++mf) {
    int row = m0 + wr * 64 + mf * 16 + lq * 4;
#pragma unroll
    for (int nf = 0; nf < NF; ++nf) {
      int col = n0 + wc * (NF * 16) + nf * 16 + la;
#pragma unroll
      for (int r = 0; r < 4; ++r)
        C[(size_t)(row + r) * N + col] = acc[mf][nf][r];
    }
  }
#undef G_STG_A
#undef G_STG_B
#undef G_RD_A
#undef G_RD_B
#undef G_MMA
}

// ---------------------------------------------------------------------------
// RoPE: read QKV fp32, write q_b (bf16 * CSC_, [B][NH][T][D]) and knew (fp32)
__global__ __launch_bounds__(256) void rope_kernel(const float* __restrict__ QKV,
                                                   const int* __restrict__ pos_ids,
                                                   unsigned short* __restrict__ q_b,
                                                   float* __restrict__ knew) {
  int idx = blockIdx.x * 256 + threadIdx.x;
  const int total = B_ * T_ * (NH_ + NKV_) * 32;
  if (idx >= total) return;
  int i = idx & 31;
  int tmp = idx >> 5;
  int hh = tmp % (NH_ + NKV_);
  int bt = tmp / (NH_ + NKV_);
  int t = bt & (T_ - 1);
  int b = bt >> 11;
  int pos = pos_ids[bt] + STEPS_;
  float inv = exp2f(-(float)i * (13.287712379549449f / 32.0f));
  float ang = (float)pos * inv;
  float sn, cs;
  sincosf(ang, &sn, &cs);
  const float* rowp = QKV + (size_t)bt * 3072;
  if (hh < NH_) {
    float x1 = rowp[hh * 64 + i];
    float x2 = rowp[hh * 64 + 32 + i];
    float y1 = (x1 * cs - x2 * sn) * CSC_;   // fold score scale into q
    float y2 = (x2 * cs + x1 * sn) * CSC_;
    size_t o = ((size_t)(b * NH_ + hh) * T_ + t) * HD_ + i;
    q_b[o] = f2bf(y1);
    q_b[o + 32] = f2bf(y2);
  } else {
    int kv = hh - NH_;
    float x1 = rowp[2048 + kv * 64 + i];
    float x2 = rowp[2048 + kv * 64 + 32 + i];
    float y1 = x1 * cs - x2 * sn;
    float y2 = x2 * cs + x1 * sn;
    size_t o = ((size_t)(b * NKV_ + kv) * T_ + t) * HD_ + i;
    knew[o] = y1;
    knew[o + 32] = y2;
  }
}

// ---------------------------------------------------------------------------
// Flash attention v2, swapped-QK^T, fused epilogue, 4 BLOCKS/CU.
//
// Changes vs round 6:
//  - sP shrunk to [4][16*64] (one f at a time) with an XOR swizzle on the
//    8B column-unit: unit u (= key>>2) stored at u ^ (la&6). Even key keeps
//    the two units of each 16B frag read adjacent; same involution applied
//    on write and read. LDS total = 16384(sK)+16384(sV)+8192(sP) = 40960 B
//    EXACTLY -> 4 blocks/CU (was 3). __launch_bounds__(256,4).
//  - V-frag loads after softmax (round-5 position) to keep VGPR <= 128
//    (the 4-waves/SIMD cap); the exposed V latency is covered by +33% TLP.
//  - keeps round 6's per-lane partial l and per-lane defer-max check.
__global__ __launch_bounds__(256, 4) void flash_kernel(const unsigned short* __restrict__ qb,
                                                       const unsigned short* __restrict__ k0b,
                                                       const unsigned short* __restrict__ v0t,
                                                       const float* __restrict__ prev_k,
                                                       const float* __restrict__ prev_v,
                                                       const float* __restrict__ knew,
                                                       const float* __restrict__ QKV,
                                                       unsigned short* __restrict__ attnout) {
  __shared__ unsigned short sK[2][64 * 64];
  __shared__ unsigned short sV[2][64 * 64];
  __shared__ unsigned short sP[4][16 * 64];

  const int tid = threadIdx.x;
  const int lane = tid & 63;
  const int wave = tid >> 6;
  const int la = lane & 15;
  const int lq = lane >> 4;
  const int swz = la & 7;
  const int swp = la & 6;   // sP column-unit swizzle key (even -> pair-safe)

  const int id = blockIdx.x;
  const int bh = (id & 7) * 8 + ((id >> 3) & 7);
  const int qt = 15 - (id >> 6);

  const size_t bhs = (size_t)bh;
  const unsigned short* gK = k0b + bhs * T_ * HD_;
  const unsigned short* gV = v0t + bhs * HD_ * T_;

  const int rb0 = qt * 128 + wave * 32;
  const int ktd = rb0 >> 6;
  const int ktmax = 2 * qt + 1;

  bf16x8 aq[2][2];
#pragma unroll
  for (int f = 0; f < 2; f++) {
    const unsigned short* qp = qb + (bhs * T_ + rb0 + f * 16 + la) * HD_;
    aq[f][0] = frag_ld(qp + lq * 8);
    aq[f][1] = frag_ld(qp + 32 + lq * 8);
  }

  f32x4 o[2][4] = {};
  float m_f[2] = {-1e30f, -1e30f};
  float l_p[2] = {0.0f, 0.0f};   // per-lane partial row-sum (lq-slice)

  const int lrow = lane >> 3;
  const int lcb = (lane & 7) ^ lrow;

  {
    unsigned short* kd = &sK[0][wave * 1024];
    unsigned short* vd = &sV[0][wave * 1024];
    async_cp16(gK + (size_t)(wave * 16 + lrow) * HD_ + lcb * 8, kd);
    async_cp16(gK + (size_t)(wave * 16 + 8 + lrow) * HD_ + lcb * 8, kd + 512);
    async_cp16(gV + (size_t)(wave * 16 + lrow) * T_ + lcb * 8, vd);
    async_cp16(gV + (size_t)(wave * 16 + 8 + lrow) * T_ + lcb * 8, vd + 512);
  }
  __syncthreads();

  int cur = 0;
  for (int kt = 0; kt <= ktmax; ++kt) {
    if (kt < ktmax) {
      const int nk = (kt + 1) * 64;
      unsigned short* kd = &sK[cur ^ 1][wave * 1024];
      unsigned short* vd = &sV[cur ^ 1][wave * 1024];
      async_cp16(gK + (size_t)(nk + wave * 16 + lrow) * HD_ + lcb * 8, kd);
      async_cp16(gK + (size_t)(nk + wave * 16 + 8 + lrow) * HD_ + lcb * 8, kd + 512);
      async_cp16(gV + (size_t)(wave * 16 + lrow) * T_ + nk + lcb * 8, vd);
      async_cp16(gV + (size_t)(wave * 16 + 8 + lrow) * T_ + nk + lcb * 8, vd + 512);
    }

    if (kt <= ktd) {
      const unsigned short* kb = &sK[cur][0];
      const unsigned short* vb = &sV[cur][0];

      bf16x8 bk0[4], bk1[4];
#pragma unroll
      for (int nb = 0; nb < 4; nb++) {
        const unsigned short* rp = kb + (nb * 16 + la) * 64;
        bk0[nb] = frag_ld(rp + ((lq ^ swz) << 3));
        bk1[nb] = frag_ld(rp + (((lq + 4) ^ swz) << 3));
      }
      // S^T = K * Q^T : lane la = q-row (frag f), key = nb*16 + lq*4 + r
      f32x4 s[2][4];
      __builtin_amdgcn_s_setprio(1);
#pragma unroll
      for (int f = 0; f < 2; f++)
#pragma unroll
        for (int nb = 0; nb < 4; nb++) {
          f32x4 z = {0.f, 0.f, 0.f, 0.f};
          z = mfma16(bk0[nb], aq[f][0], z);
          z = mfma16(bk1[nb], aq[f][1], z);
          s[f][nb] = z;
        }
      __builtin_amdgcn_s_setprio(0);

      const bool diag = (kt == ktd);
#pragma unroll
      for (int f = 0; f < 2; f++) {
        const int qrow = rb0 + f * 16 + la;
        if (diag) {
#pragma unroll
          for (int nb = 0; nb < 4; nb++)
#pragma unroll
            for (int r = 0; r < 4; r++) {
              int key = kt * 64 + nb * 16 + lq * 4 + r;
              s[f][nb][r] = (key <= qrow) ? s[f][nb][r] : -1e30f;
            }
        }
        // per-lane max over this lane's 16 keys (no cross-lane in common path)
        float t0 = fmaxf(fmaxf(s[f][0][0], s[f][0][1]), fmaxf(s[f][0][2], s[f][0][3]));
        float t1 = fmaxf(fmaxf(s[f][1][0], s[f][1][1]), fmaxf(s[f][1][2], s[f][1][3]));
        float t2 = fmaxf(fmaxf(s[f][2][0], s[f][2][1]), fmaxf(s[f][2][2], s[f][2][3]));
        float t3 = fmaxf(fmaxf(s[f][3][0], s[f][3][1]), fmaxf(s[f][3][2], s[f][3][3]));
        float tm = fmaxf(fmaxf(t0, t1), fmaxf(t2, t3));
        // defer-max (T13): rescale only if some lane's slice-max passed m+8
        const bool resc = __any(tm > m_f[f] + 8.0f);
        if (resc) {
          tm = fmaxf(tm, __shfl_xor(tm, 16));
          tm = fmaxf(tm, __shfl_xor(tm, 32));
          float mn = fmaxf(m_f[f], tm);
          float al = exp2f(m_f[f] - mn);   // row-uniform across lq
          m_f[f] = mn;
          l_p[f] *= al;
          // al lives on lane (la = qrow); O accumulator has qrow = lq*4+r
          float a0 = __shfl(al, lq * 4 + 0);
          float a1 = __shfl(al, lq * 4 + 1);
          float a2 = __shfl(al, lq * 4 + 2);
          float a3 = __shfl(al, lq * 4 + 3);
#pragma unroll
          for (int jd = 0; jd < 4; jd++) {
            o[f][jd][0] *= a0;
            o[f][jd][1] *= a1;
            o[f][jd][2] *= a2;
            o[f][jd][3] *= a3;
          }
        }
        float ls = 0.0f;
#pragma unroll
        for (int nb = 0; nb < 4; nb++)
#pragma unroll
          for (int r = 0; r < 4; r++) {
            float p = exp2f(s[f][nb][r] - m_f[f]);
            s[f][nb][r] = p;
            ls += p;
          }
        l_p[f] += ls;   // per-lane partial; lq-reduction deferred to tail
      }

      // V fragments (after softmax: VGPR-friendly; latency covered by TLP)
      bf16x8 bv0[4], bv1[4];
#pragma unroll
      for (int jd = 0; jd < 4; jd++) {
        const unsigned short* rp = vb + (jd * 16 + la) * 64;
        bv0[jd] = frag_ld(rp + ((lq ^ swz) << 3));
        bv1[jd] = frag_ld(rp + (((lq + 4) ^ swz) << 3));
      }

      // P round trip per f through the swizzled single-f sP; same-wave DS
      // ordering makes write(f=1) after read(f=0) safe without extra waits.
      unsigned short* pw = &sP[wave][0];
#pragma unroll
      for (int f = 0; f < 2; f++) {
#pragma unroll
        for (int nb = 0; nb < 4; nb++) {
          unsigned int p01 = cvtpk_bf16(s[f][nb][0], s[f][nb][1]);
          unsigned int p23 = cvtpk_bf16(s[f][nb][2], s[f][nb][3]);
          unsigned long long pq = ((unsigned long long)p23 << 32) | (unsigned long long)p01;
          *(unsigned long long*)(pw + la * 64 + (((nb * 4 + lq) ^ swp) << 2)) = pq;
        }
        bf16x8 ap0 = frag_ld(&pw[la * 64 + (((lq * 2) ^ swp) << 2)]);
        bf16x8 ap1 = frag_ld(&pw[la * 64 + ((8 + ((lq * 2) ^ swp)) << 2)]);
        __builtin_amdgcn_s_setprio(1);
#pragma unroll
        for (int jd = 0; jd < 4; jd++) {
          o[f][jd] = mfma16(ap0, bv0[jd], o[f][jd]);
          o[f][jd] = mfma16(ap1, bv1[jd], o[f][jd]);
        }
        __builtin_amdgcn_s_setprio(0);
      }
    }
    __syncthreads();
    cur ^= 1;
  }

  // finalize l: reduce the per-lane partials over the lq axis (once)
#pragma unroll
  for (int f = 0; f < 2; f++) {
    l_p[f] += __shfl_xor(l_p[f], 16);
    l_p[f] += __shfl_xor(l_p[f], 32);
  }

  // ---- fused epilogue: fold diagonal keys (prev_k[1], new k) and write bf16
  const int bI = bh >> 5;
  const int hI = bh & 31;
  const int kvI = hI >> 2;
  const size_t P1 = (size_t)B_ * NH_ * T_ * HD_;
  const float* k1base = prev_k + P1 + bhs * T_ * HD_;
  const float* v1base = prev_v + P1 + bhs * T_ * HD_;
  const float* knbase = knew + ((size_t)bI * NKV_ + kvI) * T_ * HD_;
  const float* vnbase = QKV + (size_t)bI * T_ * 3072 + 2560 + kvI * 64;
  unsigned short* aobase = attnout + (size_t)bI * T_ * (NH_ * HD_) + hI * HD_;

#pragma unroll
  for (int f = 0; f < 2; f++) {
    const int rowA = rb0 + f * 16 + la;   // dot-domain row (la), all lq share
    const float* k1p = k1base + (size_t)rowA * HD_;
    const float* knp = knbase + (size_t)rowA * HD_;
    float e1 = 0.f, e2 = 0.f;
#pragma unroll
    for (int h2 = 0; h2 < 2; h2++) {
      const int dd = h2 * 32 + lq * 8;
#pragma unroll
      for (int j = 0; j < 8; j++) {
        float qv = (float)aq[f][h2][j];   // bf16 q incl CSC_ (== old q_b read)
        e1 = fmaf(qv, k1p[dd + j], e1);
        e2 = fmaf(qv, knp[dd + j], e2);
      }
    }
    e1 += __shfl_xor(e1, 16); e1 += __shfl_xor(e1, 32);
    e2 += __shfl_xor(e2, 16); e2 += __shfl_xor(e2, 32);
    float mx = fmaxf(m_f[f], fmaxf(e1, e2));
    float w0 = exp2f(m_f[f] - mx);
    float w1 = exp2f(e1 - mx);
    float w2 = exp2f(e2 - mx);
    float inv = 1.0f / (l_p[f] * w0 + w1 + w2);
    float s0 = w0 * inv, s1 = w1 * inv, s2 = w2 * inv;
    // move per-row scalars (on lanes 0..15) to the O domain (row = lq*4+r)
    float a0[4], a1[4], a2[4];
#pragma unroll
    for (int r = 0; r < 4; r++) {
      a0[r] = __shfl(s0, lq * 4 + r);
      a1[r] = __shfl(s1, lq * 4 + r);
      a2[r] = __shfl(s2, lq * 4 + r);
    }
#pragma unroll
    for (int r = 0; r < 4; r++) {
      const int rowO = rb0 + f * 16 + lq * 4 + r;
      const float* v1p = v1base + (size_t)rowO * HD_;
      const float* vnp = vnbase + (size_t)rowO * 3072;
      unsigned short* aop = aobase + (size_t)rowO * (NH_ * HD_);
#pragma unroll
      for (int jd = 0; jd < 4; jd++) {
        int d = jd * 16 + la;
        float out = o[f][jd][r] * a0[r] + v1p[d] * a1[r] + vnp[d] * a2[r];
        aop[d] = f2bf(out);
      }
    }
  }
}

// ---------------------------------------------------------------------------
// Workspace layout (bytes; needs ws_size >= 178,257,920)
#define OFF_QKV   ((size_t)0)
#define OFF_XB    ((size_t)50331648)
#define OFF_WQKVT ((size_t)83886080)
#define OFF_WOT   ((size_t)109051904)
#define OFF_QB    ((size_t)117440512)
#define OFF_K0B   ((size_t)134217728)
#define OFF_V0T   ((size_t)150994944)
#define OFF_KNEW  ((size_t)167772160)
#define OFF_ML    ((size_t)176160768)

extern "C" void kernel_launch(void* const* d_in, const int* in_sizes, int n_in,
                              void* d_out, int out_size, void* d_ws, size_t ws_size,
                              hipStream_t stream) {
  const float* X = (const float*)d_in[0];
  const int* pos = (const int*)d_in[2];
  const float* prevk = (const float*)d_in[3];
  const float* prevv = (const float*)d_in[4];
  const float* Wq = (const float*)d_in[5];
  const float* Wk = (const float*)d_in[6];
  const float* Wv = (const float*)d_in[7];
  const float* Wo = (const float*)d_in[8];

  char* ws = (char*)d_ws;
  float* QKV = (float*)(ws + OFF_QKV);
  unsigned short* Xb = (unsigned short*)(ws + OFF_XB);
  unsigned short* WqkvT = (unsigned short*)(ws + OFF_WQKVT);
  unsigned short* attnout = (unsigned short*)(ws + OFF_WQKVT);
  unsigned short* WoT = (unsigned short*)(ws + OFF_WOT);
  unsigned short* q_b = (unsigned short*)(ws + OFF_QB);
  unsigned short* k0b = (unsigned short*)(ws + OFF_K0B);
  unsigned short* v0t = (unsigned short*)(ws + OFF_V0T);
  float* knew = (float*)(ws + OFF_KNEW);

  convert_bf16<<<16384, 256, 0, stream>>>(X, Xb, 4194304);
  transpose_wqkv<<<dim3(48, 64), 256, 0, stream>>>(Wq, Wk, Wv, WqkvT);
  transpose_f32_bf16_ld<<<dim3(32, 32), 256, 0, stream>>>(Wo, WoT, 2048, 2048, 2048);
  convert_bf16<<<8192, 256, 0, stream>>>(prevk, k0b, 2097152);
  transpose_v0<<<dim3(32, 64), 256, 0, stream>>>(prevv, v0t);

  // QKV GEMM: M=4096, N=3072, K=4096; BM=128, BN=384 -> grid 32x8 = 256
  gemm128_bt<6><<<dim3(32, 8), 512, 0, stream>>>(Xb, WqkvT, QKV, 4096, 3072, 4096);

  rope_kernel<<<20480, 256, 0, stream>>>(QKV, pos, q_b, knew);

  // flash with fused diagonal-key epilogue -> writes attnout bf16 directly
  flash_kernel<<<1024, 256, 0, stream>>>(q_b, k0b, v0t, prevk, prevv, knew, QKV, attnout);

  // Wo GEMM: M=4096, N=2048, K=2048; BM=128, BN=256 -> grid 32x8 = 256
  gemm128_bt<4><<<dim3(32, 8), 512, 0, stream>>>(attnout, WoT, (float*)d_out, 4096, 2048, 2048);
}

// Round 8
// 513.519 us; speedup vs baseline: 1.0249x; 1.0249x over previous
//
#include <hip/hip_runtime.h>

// Problem constants
#define B_    2
#define T_    2048
#define HID_  2048
#define NH_   32
#define NKV_  8
#define HD_   64
#define STEPS_ 2
#define SCALE_ 0.125f
// SCALE * log2(e): scores kept in exp2 domain throughout (folded into q at RoPE)
#define CSC_  0.18033688011112042f

typedef float   f32x4  __attribute__((ext_vector_type(4)));
typedef __bf16  bf16x8 __attribute__((ext_vector_type(8)));
typedef unsigned short u16x8 __attribute__((ext_vector_type(8)));

__device__ __forceinline__ unsigned short f2bf(float f) {
  unsigned int u = __builtin_bit_cast(unsigned int, f);
  u = (u + 0x7fffu + ((u >> 16) & 1u)) >> 16;
  return (unsigned short)u;
}
__device__ __forceinline__ float bf2f(unsigned short h) {
  unsigned int u = ((unsigned int)h) << 16;
  return __builtin_bit_cast(float, u);
}
__device__ __forceinline__ bf16x8 frag_ld(const unsigned short* p) {
  u16x8 v = *(const u16x8*)p;
  return __builtin_bit_cast(bf16x8, v);
}
__device__ __forceinline__ f32x4 mfma16(bf16x8 a, bf16x8 b, f32x4 c) {
  return __builtin_amdgcn_mfma_f32_16x16x32_bf16(a, b, c, 0, 0, 0);
}
__device__ __forceinline__ void async_cp16(const void* g, void* l) {
  __builtin_amdgcn_global_load_lds(
      (const __attribute__((address_space(1))) void*)g,
      (__attribute__((address_space(3))) void*)l, 16, 0, 0);
}
// HW packed f32->bf16 (RNE), no builtin on gfx950 -> inline asm (guide T12)
__device__ __forceinline__ unsigned int cvtpk_bf16(float lo, float hi) {
  unsigned int r;
  asm("v_cvt_pk_bf16_f32 %0, %1, %2" : "=v"(r) : "v"(lo), "v"(hi));
  return r;
}

// ---------------------------------------------------------------------------
// elementwise fp32 -> bf16 convert (float4 per thread)
__global__ __launch_bounds__(256) void convert_bf16(const float* __restrict__ in,
                                                    unsigned short* __restrict__ out,
                                                    int n4) {
  int idx = blockIdx.x * 256 + threadIdx.x;
  if (idx < n4) {
    float4 v = ((const float4*)in)[idx];
    ushort4 o;
    o.x = f2bf(v.x); o.y = f2bf(v.y); o.z = f2bf(v.z); o.w = f2bf(v.w);
    ((ushort4*)out)[idx] = o;
  }
}

// merged Wq/Wk/Wv transpose+convert into WqkvT [3072][4096]
//  bx 0..31 -> Wq (4096x2048), 32..39 -> Wk (4096x512), 40..47 -> Wv
__global__ __launch_bounds__(256) void transpose_wqkv(const float* __restrict__ Wq,
                                                      const float* __restrict__ Wk,
                                                      const float* __restrict__ Wv,
                                                      unsigned short* __restrict__ out) {
  __shared__ float tile[64][65];
  int bx = blockIdx.x;
  const float* in; int N; int nbase;
  if (bx < 32)      { in = Wq; N = 2048; nbase = 0;    }
  else if (bx < 40) { in = Wk; N = 512;  nbase = 2048; bx -= 32; }
  else              { in = Wv; N = 512;  nbase = 2560; bx -= 40; }
  int n0 = bx * 64, k0 = blockIdx.y * 64;
  int c = threadIdx.x & 63, w = threadIdx.x >> 6;
#pragma unroll
  for (int i = 0; i < 16; i++) {
    int r = w * 16 + i;
    tile[r][c] = in[(size_t)(k0 + r) * N + n0 + c];
  }
  __syncthreads();
#pragma unroll
  for (int i = 0; i < 16; i++) {
    int rr = w * 16 + i;
    out[(size_t)(nbase + n0 + rr) * 4096 + k0 + c] = f2bf(tile[c][rr]);
  }
}

// transpose + convert: in (K x N fp32 row-major) -> out (N x K bf16, ld=ldo)
__global__ __launch_bounds__(256) void transpose_f32_bf16_ld(const float* __restrict__ in,
                                                             unsigned short* __restrict__ out,
                                                             int K, int N, int ldo) {
  __shared__ float tile[64][65];
  int n0 = blockIdx.x * 64, k0 = blockIdx.y * 64;
  int c = threadIdx.x & 63, w = threadIdx.x >> 6;
#pragma unroll
  for (int i = 0; i < 16; i++) {
    int r = w * 16 + i;
    tile[r][c] = in[(size_t)(k0 + r) * N + n0 + c];
  }
  __syncthreads();
#pragma unroll
  for (int i = 0; i < 16; i++) {
    int rr = w * 16 + i;
    out[(size_t)(n0 + rr) * ldo + k0 + c] = f2bf(tile[c][rr]);
  }
}

// v0 (B*NH slabs of [T][D] fp32) -> v0t bf16 [B*NH][D][T]
__global__ __launch_bounds__(256) void transpose_v0(const float* __restrict__ v0,
                                                    unsigned short* __restrict__ v0t) {
  __shared__ float tile[64][65];
  int s0 = blockIdx.x * 64;
  int bh = blockIdx.y;
  const float* src = v0 + (size_t)bh * T_ * HD_;
  unsigned short* dst = v0t + (size_t)bh * HD_ * T_;
  int c = threadIdx.x & 63, w = threadIdx.x >> 6;
#pragma unroll
  for (int i = 0; i < 16; i++) {
    int r = w * 16 + i;
    tile[r][c] = src[(size_t)(s0 + r) * HD_ + c];
  }
  __syncthreads();
#pragma unroll
  for (int i = 0; i < 16; i++) {
    int rr = w * 16 + i;
    dst[(size_t)rr * T_ + s0 + c] = f2bf(tile[c][rr]);
  }
}

// ---------------------------------------------------------------------------
// 128 x (NF*64) 8-phase bf16 GEMM: C(MxN fp32) = A(MxK) * Bt(NxK)^T
// (exact round-6 version -- verified at 503 us; no XCD swizzle)
// ---------------------------------------------------------------------------
#define SBAR  do { __builtin_amdgcn_sched_barrier(0); __builtin_amdgcn_s_barrier(); \
                   __builtin_amdgcn_sched_barrier(0); } while (0)
#define LGKM0 do { asm volatile("s_waitcnt lgkmcnt(0)" ::: "memory"); \
                   __builtin_amdgcn_sched_barrier(0); } while (0)
#define VM2   do { asm volatile("s_waitcnt vmcnt(2)" ::: "memory"); } while (0)
#define VM0   do { asm volatile("s_waitcnt vmcnt(0)" ::: "memory"); } while (0)

template <int NF>
__global__ __launch_bounds__(512, 2) void gemm128_bt(const unsigned short* __restrict__ A,
                                                     const unsigned short* __restrict__ Bt,
                                                     float* __restrict__ C,
                                                     int M, int N, int K) {
  constexpr int NHF = NF / 2;             // B frags per qn group per wave
  constexpr int BROWS = 128 + NF * 64;    // rows staged per buffer
  __shared__ __attribute__((aligned(128))) unsigned short smem[2][BROWS * 64];

  const int tid  = threadIdx.x;
  const int lane = tid & 63;
  const int wid  = tid >> 6;      // 0..7
  const int wr   = wid >> 2;      // 0..1  (M half: 64 rows)
  const int wc   = wid & 3;       // 0..3  (N quarter: NF*16 cols)
  const int la   = lane & 15;
  const int lq   = lane >> 4;
  const int sw   = la & 7;        // read-side swizzle key (row&7 == la&7)
  const int m0   = blockIdx.x * 128;
  const int n0   = blockIdx.y * (NF * 64);

  // staging: chunk = wid*2+is (1 KiB, 8 rows); lane covers physical
  // (row = chunk*8 + (lane>>3), slot = lane&7); fetches logical slot
  // (lane&7)^(row&7) so the linear DMA image realizes the XOR swizzle.
  const int sr = lane >> 3;
  const int sl = (lane & 7) ^ sr;

  const unsigned short* gA[2];
  const unsigned short* gB[NHF][2];
#pragma unroll
  for (int is = 0; is < 2; ++is) {
    int r = (wid * 2 + is) * 8 + sr;
    gA[is] = A + (size_t)(m0 + r) * K + sl * 8;
#pragma unroll
    for (int u = 0; u < NHF; ++u)
      gB[u][is] = Bt + (size_t)(n0 + u * 128 + r) * K + sl * 8;
  }

#define G_STG_A(buf, kt) do { \
    async_cp16(gA[0] + (size_t)(kt) * 64, &smem[buf][(wid * 2 + 0) * 512]); \
    async_cp16(gA[1] + (size_t)(kt) * 64, &smem[buf][(wid * 2 + 1) * 512]); \
  } while (0)
#define G_STG_B(buf, u, kt) do { \
    async_cp16(gB[u][0] + (size_t)(kt) * 64, &smem[buf][(128 + (u) * 128) * 64 + (wid * 2 + 0) * 512]); \
    async_cp16(gB[u][1] + (size_t)(kt) * 64, &smem[buf][(128 + (u) * 128) * 64 + (wid * 2 + 1) * 512]); \
  } while (0)

  f32x4  acc[4][NF] = {};
  bf16x8 aR[2][2], b0r[NHF][2], b1r[NHF][2];

#define G_RD_A(buf, qm) do { \
    const unsigned short* rp_ = &smem[buf][0]; \
    _Pragma("unroll") \
    for (int i_ = 0; i_ < 2; ++i_) { \
      int ro_ = (wr * 64 + (qm) * 32 + i_ * 16 + la) * 64; \
      aR[i_][0] = frag_ld(rp_ + ro_ + (((0 + lq) ^ sw) << 3)); \
      aR[i_][1] = frag_ld(rp_ + ro_ + (((4 + lq) ^ sw) << 3)); \
    } \
  } while (0)
#define G_RD_B(buf, qn, breg) do { \
    const unsigned short* rp_ = &smem[buf][128 * 64]; \
    _Pragma("unroll") \
    for (int j_ = 0; j_ < NHF; ++j_) { \
      int ro_ = (wc * (NF * 16) + (qn) * (NF * 8) + j_ * 16 + la) * 64; \
      breg[j_][0] = frag_ld(rp_ + ro_ + (((0 + lq) ^ sw) << 3)); \
      breg[j_][1] = frag_ld(rp_ + ro_ + (((4 + lq) ^ sw) << 3)); \
    } \
  } while (0)
#define G_MMA(qm, qn, breg) do { \
    _Pragma("unroll") \
    for (int i_ = 0; i_ < 2; ++i_) \
      _Pragma("unroll") \
      for (int j_ = 0; j_ < NHF; ++j_) { \
        f32x4 c_ = acc[(qm) * 2 + i_][(qn) * NHF + j_]; \
        c_ = mfma16(aR[i_][0], breg[j_][0], c_); \
        c_ = mfma16(aR[i_][1], breg[j_][1], c_); \
        acc[(qm) * 2 + i_][(qn) * NHF + j_] = c_; \
      } \
  } while (0)

  // prologue: tile0 fully -> buf0; tile1's prev-P8-role slot -> buf1.
  G_STG_A(0, 0);
#pragma unroll
  for (int u = 0; u < NHF; ++u) G_STG_B(0, u, 0);
  if constexpr (NF == 6) G_STG_B(1, 2, 1); else G_STG_A(1, 1);
  VM2;   // tile0's slots landed; the buf1 slot may stay in flight
  SBAR;

  const int NI = K >> 7;   // iterations of 2 K-tiles (K multiple of 128)
  for (int it = 0; it < NI; ++it) {
    const int e = it * 2;
    const bool pf = (it + 1 < NI);
    // ---- P1
    G_RD_A(0, 0);
    G_RD_B(0, 0, b0r);
    if constexpr (NF == 6) G_STG_A(1, e + 1); else G_STG_B(1, 0, e + 1);
    SBAR; LGKM0;
    __builtin_amdgcn_s_setprio(1); G_MMA(0, 0, b0r); __builtin_amdgcn_s_setprio(0);
    SBAR;
    // ---- P2
    G_RD_B(0, 1, b1r);
    if constexpr (NF == 6) G_STG_B(1, 0, e + 1); else G_STG_B(1, 1, e + 1);
    SBAR; LGKM0;
    __builtin_amdgcn_s_setprio(1); G_MMA(0, 1, b1r); __builtin_amdgcn_s_setprio(0);
    SBAR;
    // ---- P3
    G_RD_A(0, 1);
    if constexpr (NF == 6) G_STG_B(1, 1, e + 1);
    SBAR; LGKM0;
    __builtin_amdgcn_s_setprio(1); G_MMA(1, 1, b1r); __builtin_amdgcn_s_setprio(0);
    SBAR;
    // ---- P4
    if (pf) G_STG_A(0, e + 2);
    SBAR; LGKM0;
    __builtin_amdgcn_s_setprio(1); G_MMA(1, 0, b0r); __builtin_amdgcn_s_setprio(0);
    if (pf) { VM2; } else { VM0; }
    SBAR;
    // ---- P5
    G_RD_A(1, 0);
    G_RD_B(1, 0, b0r);
    if (pf) G_STG_B(0, 0, e + 2);
    SBAR; LGKM0;
    __builtin_amdgcn_s_setprio(1); G_MMA(0, 0, b0r); __builtin_amdgcn_s_setprio(0);
    SBAR;
    // ---- P6
    G_RD_B(1, 1, b1r);
    if (pf) G_STG_B(0, 1, e + 2);
    SBAR; LGKM0;
    __builtin_amdgcn_s_setprio(1); G_MMA(0, 1, b1r); __builtin_amdgcn_s_setprio(0);
    SBAR;
    // ---- P7
    G_RD_A(1, 1);
    if constexpr (NF == 6) { if (pf) G_STG_B(0, 2, e + 2); }
    SBAR; LGKM0;
    __builtin_amdgcn_s_setprio(1); G_MMA(1, 1, b1r); __builtin_amdgcn_s_setprio(0);
    SBAR;
    // ---- P8
    if constexpr (NF == 6) { if (pf) G_STG_B(1, 2, e + 3); }
    else                   { if (pf) G_STG_A(1, e + 3); }
    SBAR; LGKM0;
    __builtin_amdgcn_s_setprio(1); G_MMA(1, 0, b0r); __builtin_amdgcn_s_setprio(0);
    VM2;
    SBAR;
  }

  // epilogue: C[row, col], col = frag col + la, row = lq*4 + r within frag
#pragma unroll
  for (int mf = 0; mf < 4; ++mf) {
    int row = m0 + wr * 64 + mf * 16 + lq * 4;
#pragma unroll
    for (int nf = 0; nf < NF; ++nf) {
      int col = n0 + wc * (NF * 16) + nf * 16 + la;
#pragma unroll
      for (int r = 0; r < 4; ++r)
        C[(size_t)(row + r) * N + col] = acc[mf][nf][r];
    }
  }
#undef G_STG_A
#undef G_STG_B
#undef G_RD_A
#undef G_RD_B
#undef G_MMA
}

// ---------------------------------------------------------------------------
// RoPE: read QKV fp32, write q_b (bf16 * CSC_, [B][NH][T][D]) and knew (fp32)
__global__ __launch_bounds__(256) void rope_kernel(const float* __restrict__ QKV,
                                                   const int* __restrict__ pos_ids,
                                                   unsigned short* __restrict__ q_b,
                                                   float* __restrict__ knew) {
  int idx = blockIdx.x * 256 + threadIdx.x;
  const int total = B_ * T_ * (NH_ + NKV_) * 32;
  if (idx >= total) return;
  int i = idx & 31;
  int tmp = idx >> 5;
  int hh = tmp % (NH_ + NKV_);
  int bt = tmp / (NH_ + NKV_);
  int t = bt & (T_ - 1);
  int b = bt >> 11;
  int pos = pos_ids[bt] + STEPS_;
  float inv = exp2f(-(float)i * (13.287712379549449f / 32.0f));
  float ang = (float)pos * inv;
  float sn, cs;
  sincosf(ang, &sn, &cs);
  const float* rowp = QKV + (size_t)bt * 3072;
  if (hh < NH_) {
    float x1 = rowp[hh * 64 + i];
    float x2 = rowp[hh * 64 + 32 + i];
    float y1 = (x1 * cs - x2 * sn) * CSC_;   // fold score scale into q
    float y2 = (x2 * cs + x1 * sn) * CSC_;
    size_t o = ((size_t)(b * NH_ + hh) * T_ + t) * HD_ + i;
    q_b[o] = f2bf(y1);
    q_b[o + 32] = f2bf(y2);
  } else {
    int kv = hh - NH_;
    float x1 = rowp[2048 + kv * 64 + i];
    float x2 = rowp[2048 + kv * 64 + 32 + i];
    float y1 = x1 * cs - x2 * sn;
    float y2 = x2 * cs + x1 * sn;
    size_t o = ((size_t)(b * NKV_ + kv) * T_ + t) * HD_ + i;
    knew[o] = y1;
    knew[o + 32] = y2;
  }
}

// ---------------------------------------------------------------------------
// Flash attention v2, swapped-QK^T, fused epilogue, low-latency softmax.
// (exact round-6 version -- verified at 503 us. sP stride 72 is at the LDS
// bandwidth floor for b64 writes; stride-64 "fix" measured 2x worse, r7.)
__global__ __launch_bounds__(256, 3) void flash_kernel(const unsigned short* __restrict__ qb,
                                                       const unsigned short* __restrict__ k0b,
                                                       const unsigned short* __restrict__ v0t,
                                                       const float* __restrict__ prev_k,
                                                       const float* __restrict__ prev_v,
                                                       const float* __restrict__ knew,
                                                       const float* __restrict__ QKV,
                                                       unsigned short* __restrict__ attnout) {
  __shared__ unsigned short sK[2][64 * 64];
  __shared__ unsigned short sV[2][64 * 64];
  __shared__ unsigned short sP[4][2][16 * 72];

  const int tid = threadIdx.x;
  const int lane = tid & 63;
  const int wave = tid >> 6;
  const int la = lane & 15;
  const int lq = lane >> 4;
  const int swz = la & 7;

  const int id = blockIdx.x;
  const int bh = (id & 7) * 8 + ((id >> 3) & 7);
  const int qt = 15 - (id >> 6);

  const size_t bhs = (size_t)bh;
  const unsigned short* gK = k0b + bhs * T_ * HD_;
  const unsigned short* gV = v0t + bhs * HD_ * T_;

  const int rb0 = qt * 128 + wave * 32;
  const int ktd = rb0 >> 6;
  const int ktmax = 2 * qt + 1;

  bf16x8 aq[2][2];
#pragma unroll
  for (int f = 0; f < 2; f++) {
    const unsigned short* qp = qb + (bhs * T_ + rb0 + f * 16 + la) * HD_;
    aq[f][0] = frag_ld(qp + lq * 8);
    aq[f][1] = frag_ld(qp + 32 + lq * 8);
  }

  f32x4 o[2][4] = {};
  float m_f[2] = {-1e30f, -1e30f};
  float l_p[2] = {0.0f, 0.0f};   // per-lane partial row-sum (lq-slice)

  const int lrow = lane >> 3;
  const int lcb = (lane & 7) ^ lrow;

  {
    unsigned short* kd = &sK[0][wave * 1024];
    unsigned short* vd = &sV[0][wave * 1024];
    async_cp16(gK + (size_t)(wave * 16 + lrow) * HD_ + lcb * 8, kd);
    async_cp16(gK + (size_t)(wave * 16 + 8 + lrow) * HD_ + lcb * 8, kd + 512);
    async_cp16(gV + (size_t)(wave * 16 + lrow) * T_ + lcb * 8, vd);
    async_cp16(gV + (size_t)(wave * 16 + 8 + lrow) * T_ + lcb * 8, vd + 512);
  }
  __syncthreads();

  int cur = 0;
  for (int kt = 0; kt <= ktmax; ++kt) {
    if (kt < ktmax) {
      const int nk = (kt + 1) * 64;
      unsigned short* kd = &sK[cur ^ 1][wave * 1024];
      unsigned short* vd = &sV[cur ^ 1][wave * 1024];
      async_cp16(gK + (size_t)(nk + wave * 16 + lrow) * HD_ + lcb * 8, kd);
      async_cp16(gK + (size_t)(nk + wave * 16 + 8 + lrow) * HD_ + lcb * 8, kd + 512);
      async_cp16(gV + (size_t)(wave * 16 + lrow) * T_ + nk + lcb * 8, vd);
      async_cp16(gV + (size_t)(wave * 16 + 8 + lrow) * T_ + nk + lcb * 8, vd + 512);
    }

    if (kt <= ktd) {
      const unsigned short* kb = &sK[cur][0];
      const unsigned short* vb = &sV[cur][0];

      bf16x8 bk0[4], bk1[4];
#pragma unroll
      for (int nb = 0; nb < 4; nb++) {
        const unsigned short* rp = kb + (nb * 16 + la) * 64;
        bk0[nb] = frag_ld(rp + ((lq ^ swz) << 3));
        bk1[nb] = frag_ld(rp + (((lq + 4) ^ swz) << 3));
      }
      // S^T = K * Q^T : lane la = q-row (frag f), key = nb*16 + lq*4 + r
      f32x4 s[2][4];
      __builtin_amdgcn_s_setprio(1);
#pragma unroll
      for (int f = 0; f < 2; f++)
#pragma unroll
        for (int nb = 0; nb < 4; nb++) {
          f32x4 z = {0.f, 0.f, 0.f, 0.f};
          z = mfma16(bk0[nb], aq[f][0], z);
          z = mfma16(bk1[nb], aq[f][1], z);
          s[f][nb] = z;
        }
      __builtin_amdgcn_s_setprio(0);

      // V fragment reads issued early: DS latency hides under softmax VALU
      bf16x8 bv0[4], bv1[4];
#pragma unroll
      for (int jd = 0; jd < 4; jd++) {
        const unsigned short* rp = vb + (jd * 16 + la) * 64;
        bv0[jd] = frag_ld(rp + ((lq ^ swz) << 3));
        bv1[jd] = frag_ld(rp + (((lq + 4) ^ swz) << 3));
      }

      const bool diag = (kt == ktd);
#pragma unroll
      for (int f = 0; f < 2; f++) {
        const int qrow = rb0 + f * 16 + la;
        if (diag) {
#pragma unroll
          for (int nb = 0; nb < 4; nb++)
#pragma unroll
            for (int r = 0; r < 4; r++) {
              int key = kt * 64 + nb * 16 + lq * 4 + r;
              s[f][nb][r] = (key <= qrow) ? s[f][nb][r] : -1e30f;
            }
        }
        // per-lane max over this lane's 16 keys (no cross-lane in common path)
        float t0 = fmaxf(fmaxf(s[f][0][0], s[f][0][1]), fmaxf(s[f][0][2], s[f][0][3]));
        float t1 = fmaxf(fmaxf(s[f][1][0], s[f][1][1]), fmaxf(s[f][1][2], s[f][1][3]));
        float t2 = fmaxf(fmaxf(s[f][2][0], s[f][2][1]), fmaxf(s[f][2][2], s[f][2][3]));
        float t3 = fmaxf(fmaxf(s[f][3][0], s[f][3][1]), fmaxf(s[f][3][2], s[f][3][3]));
        float tm = fmaxf(fmaxf(t0, t1), fmaxf(t2, t3));
        // defer-max (T13): rescale only if some lane's slice-max passed m+8
        const bool resc = __any(tm > m_f[f] + 8.0f);
        if (resc) {
          tm = fmaxf(tm, __shfl_xor(tm, 16));
          tm = fmaxf(tm, __shfl_xor(tm, 32));
          float mn = fmaxf(m_f[f], tm);
          float al = exp2f(m_f[f] - mn);   // row-uniform across lq
          m_f[f] = mn;
          l_p[f] *= al;
          // al lives on lane (la = qrow); O accumulator has qrow = lq*4+r
          float a0 = __shfl(al, lq * 4 + 0);
          float a1 = __shfl(al, lq * 4 + 1);
          float a2 = __shfl(al, lq * 4 + 2);
          float a3 = __shfl(al, lq * 4 + 3);
#pragma unroll
          for (int jd = 0; jd < 4; jd++) {
            o[f][jd][0] *= a0;
            o[f][jd][1] *= a1;
            o[f][jd][2] *= a2;
            o[f][jd][3] *= a3;
          }
        }
        float ls = 0.0f;
#pragma unroll
        for (int nb = 0; nb < 4; nb++)
#pragma unroll
          for (int r = 0; r < 4; r++) {
            float p = exp2f(s[f][nb][r] - m_f[f]);
            s[f][nb][r] = p;
            ls += p;
          }
        l_p[f] += ls;   // per-lane partial; lq-reduction deferred to tail
        // write this f's P into its own sP half (both halves live at once)
        unsigned short* pw = &sP[wave][f][0];
#pragma unroll
        for (int nb = 0; nb < 4; nb++) {
          unsigned int p01 = cvtpk_bf16(s[f][nb][0], s[f][nb][1]);
          unsigned int p23 = cvtpk_bf16(s[f][nb][2], s[f][nb][3]);
          unsigned long long pq = ((unsigned long long)p23 << 32) | (unsigned long long)p01;
          *(unsigned long long*)(pw + la * 72 + nb * 16 + lq * 4) = pq;
        }
      }

      // PV: one LDS round-trip wait covers both f halves
#pragma unroll
      for (int f = 0; f < 2; f++) {
        const unsigned short* pr = &sP[wave][f][0];
        bf16x8 ap0 = frag_ld(&pr[la * 72 + lq * 8]);
        bf16x8 ap1 = frag_ld(&pr[la * 72 + 32 + lq * 8]);
        __builtin_amdgcn_s_setprio(1);
#pragma unroll
        for (int jd = 0; jd < 4; jd++) {
          o[f][jd] = mfma16(ap0, bv0[jd], o[f][jd]);
          o[f][jd] = mfma16(ap1, bv1[jd], o[f][jd]);
        }
        __builtin_amdgcn_s_setprio(0);
      }
    }
    __syncthreads();
    cur ^= 1;
  }

  // finalize l: reduce the per-lane partials over the lq axis (once)
#pragma unroll
  for (int f = 0; f < 2; f++) {
    l_p[f] += __shfl_xor(l_p[f], 16);
    l_p[f] += __shfl_xor(l_p[f], 32);
  }

  // ---- fused epilogue: fold diagonal keys (prev_k[1], new k) and write bf16
  const int bI = bh >> 5;
  const int hI = bh & 31;
  const int kvI = hI >> 2;
  const size_t P1 = (size_t)B_ * NH_ * T_ * HD_;
  const float* k1base = prev_k + P1 + bhs * T_ * HD_;
  const float* v1base = prev_v + P1 + bhs * T_ * HD_;
  const float* knbase = knew + ((size_t)bI * NKV_ + kvI) * T_ * HD_;
  const float* vnbase = QKV + (size_t)bI * T_ * 3072 + 2560 + kvI * 64;
  unsigned short* aobase = attnout + (size_t)bI * T_ * (NH_ * HD_) + hI * HD_;

#pragma unroll
  for (int f = 0; f < 2; f++) {
    const int rowA = rb0 + f * 16 + la;   // dot-domain row (la), all lq share
    const float* k1p = k1base + (size_t)rowA * HD_;
    const float* knp = knbase + (size_t)rowA * HD_;
    float e1 = 0.f, e2 = 0.f;
#pragma unroll
    for (int h2 = 0; h2 < 2; h2++) {
      const int dd = h2 * 32 + lq * 8;
#pragma unroll
      for (int j = 0; j < 8; j++) {
        float qv = (float)aq[f][h2][j];   // bf16 q incl CSC_ (== old q_b read)
        e1 = fmaf(qv, k1p[dd + j], e1);
        e2 = fmaf(qv, knp[dd + j], e2);
      }
    }
    e1 += __shfl_xor(e1, 16); e1 += __shfl_xor(e1, 32);
    e2 += __shfl_xor(e2, 16); e2 += __shfl_xor(e2, 32);
    float mx = fmaxf(m_f[f], fmaxf(e1, e2));
    float w0 = exp2f(m_f[f] - mx);
    float w1 = exp2f(e1 - mx);
    float w2 = exp2f(e2 - mx);
    float inv = 1.0f / (l_p[f] * w0 + w1 + w2);
    float s0 = w0 * inv, s1 = w1 * inv, s2 = w2 * inv;
    // move per-row scalars (on lanes 0..15) to the O domain (row = lq*4+r)
    float a0[4], a1[4], a2[4];
#pragma unroll
    for (int r = 0; r < 4; r++) {
      a0[r] = __shfl(s0, lq * 4 + r);
      a1[r] = __shfl(s1, lq * 4 + r);
      a2[r] = __shfl(s2, lq * 4 + r);
    }
#pragma unroll
    for (int r = 0; r < 4; r++) {
      const int rowO = rb0 + f * 16 + lq * 4 + r;
      const float* v1p = v1base + (size_t)rowO * HD_;
      const float* vnp = vnbase + (size_t)rowO * 3072;
      unsigned short* aop = aobase + (size_t)rowO * (NH_ * HD_);
#pragma unroll
      for (int jd = 0; jd < 4; jd++) {
        int d = jd * 16 + la;
        float out = o[f][jd][r] * a0[r] + v1p[d] * a1[r] + vnp[d] * a2[r];
        aop[d] = f2bf(out);
      }
    }
  }
}

// ---------------------------------------------------------------------------
// Workspace layout (bytes; needs ws_size >= 178,257,920)
#define OFF_QKV   ((size_t)0)
#define OFF_XB    ((size_t)50331648)
#define OFF_WQKVT ((size_t)83886080)
#define OFF_WOT   ((size_t)109051904)
#define OFF_QB    ((size_t)117440512)
#define OFF_K0B   ((size_t)134217728)
#define OFF_V0T   ((size_t)150994944)
#define OFF_KNEW  ((size_t)167772160)
#define OFF_ML    ((size_t)176160768)

extern "C" void kernel_launch(void* const* d_in, const int* in_sizes, int n_in,
                              void* d_out, int out_size, void* d_ws, size_t ws_size,
                              hipStream_t stream) {
  const float* X = (const float*)d_in[0];
  const int* pos = (const int*)d_in[2];
  const float* prevk = (const float*)d_in[3];
  const float* prevv = (const float*)d_in[4];
  const float* Wq = (const float*)d_in[5];
  const float* Wk = (const float*)d_in[6];
  const float* Wv = (const float*)d_in[7];
  const float* Wo = (const float*)d_in[8];

  char* ws = (char*)d_ws;
  float* QKV = (float*)(ws + OFF_QKV);
  unsigned short* Xb = (unsigned short*)(ws + OFF_XB);
  unsigned short* WqkvT = (unsigned short*)(ws + OFF_WQKVT);
  unsigned short* attnout = (unsigned short*)(ws + OFF_WQKVT);
  unsigned short* WoT = (unsigned short*)(ws + OFF_WOT);
  unsigned short* q_b = (unsigned short*)(ws + OFF_QB);
  unsigned short* k0b = (unsigned short*)(ws + OFF_K0B);
  unsigned short* v0t = (unsigned short*)(ws + OFF_V0T);
  float* knew = (float*)(ws + OFF_KNEW);

  convert_bf16<<<16384, 256, 0, stream>>>(X, Xb, 4194304);
  transpose_wqkv<<<dim3(48, 64), 256, 0, stream>>>(Wq, Wk, Wv, WqkvT);
  transpose_f32_bf16_ld<<<dim3(32, 32), 256, 0, stream>>>(Wo, WoT, 2048, 2048, 2048);
  convert_bf16<<<8192, 256, 0, stream>>>(prevk, k0b, 2097152);
  transpose_v0<<<dim3(32, 64), 256, 0, stream>>>(prevv, v0t);

  // QKV GEMM: M=4096, N=3072, K=4096; BM=128, BN=384 -> grid 32x8 = 256
  gemm128_bt<6><<<dim3(32, 8), 512, 0, stream>>>(Xb, WqkvT, QKV, 4096, 3072, 4096);

  rope_kernel<<<20480, 256, 0, stream>>>(QKV, pos, q_b, knew);

  // flash with fused diagonal-key epilogue -> writes attnout bf16 directly
  flash_kernel<<<1024, 256, 0, stream>>>(q_b, k0b, v0t, prevk, prevv, knew, QKV, attnout);

  // Wo GEMM: M=4096, N=2048, K=2048; BM=128, BN=256 -> grid 32x8 = 256
  gemm128_bt<4><<<dim3(32, 8), 512, 0, stream>>>(attnout, WoT, (float*)d_out, 4096, 2048, 2048);
}

// Round 10
// 491.854 us; speedup vs baseline: 1.0700x; 1.0440x over previous
//
#include <hip/hip_runtime.h>

// Problem constants
#define B_    2
#define T_    2048
#define HID_  2048
#define NH_   32
#define NKV_  8
#define HD_   64
#define STEPS_ 2
#define SCALE_ 0.125f
// SCALE * log2(e): scores kept in exp2 domain throughout (folded into q at RoPE)
#define CSC_  0.18033688011112042f

typedef float   f32x4  __attribute__((ext_vector_type(4)));
typedef __bf16  bf16x8 __attribute__((ext_vector_type(8)));
typedef unsigned short u16x8 __attribute__((ext_vector_type(8)));

__device__ __forceinline__ unsigned short f2bf(float f) {
  unsigned int u = __builtin_bit_cast(unsigned int, f);
  u = (u + 0x7fffu + ((u >> 16) & 1u)) >> 16;
  return (unsigned short)u;
}
__device__ __forceinline__ float bf2f(unsigned short h) {
  unsigned int u = ((unsigned int)h) << 16;
  return __builtin_bit_cast(float, u);
}
__device__ __forceinline__ bf16x8 frag_ld(const unsigned short* p) {
  u16x8 v = *(const u16x8*)p;
  return __builtin_bit_cast(bf16x8, v);
}
__device__ __forceinline__ f32x4 mfma16(bf16x8 a, bf16x8 b, f32x4 c) {
  return __builtin_amdgcn_mfma_f32_16x16x32_bf16(a, b, c, 0, 0, 0);
}
__device__ __forceinline__ void async_cp16(const void* g, void* l) {
  __builtin_amdgcn_global_load_lds(
      (const __attribute__((address_space(1))) void*)g,
      (__attribute__((address_space(3))) void*)l, 16, 0, 0);
}
// HW packed f32->bf16 (RNE), no builtin on gfx950 -> inline asm (guide T12)
__device__ __forceinline__ unsigned int cvtpk_bf16(float lo, float hi) {
  unsigned int r;
  asm("v_cvt_pk_bf16_f32 %0, %1, %2" : "=v"(r) : "v"(lo), "v"(hi));
  return r;
}

// ---------------------------------------------------------------------------
// MERGED preprocessing: one dispatch, block-range switch.
//  [0, 16384)          convert X fp32 -> Xb bf16            (4 f32/thread)
//  [16384, 24576)      convert prev_k[0] -> k0b bf16
//  [24576, 26112)      transpose Wq/Wk/Wv -> WqkvT (128-wide k-tiles)
//  [26112, 26624)      transpose Wo -> WoT
//  [26624, 27648)      transpose prev_v[0] slabs -> v0t
// Transposes: tile 64 n x 128 k, f32 LDS [128][65] (load 2-way bank = free,
// read-back 4-way = 1.58x, off critical path); each lane writes ushort2 ->
// 256 B contiguous write runs per wave-row (2x the old 64-wide tiles).
__global__ __launch_bounds__(256) void preproc(const float* __restrict__ X,
                                               const float* __restrict__ prevk,
                                               const float* __restrict__ prevv,
                                               const float* __restrict__ Wq,
                                               const float* __restrict__ Wk,
                                               const float* __restrict__ Wv,
                                               const float* __restrict__ Wo,
                                               unsigned short* __restrict__ Xb,
                                               unsigned short* __restrict__ k0b,
                                               unsigned short* __restrict__ WqkvT,
                                               unsigned short* __restrict__ WoT,
                                               unsigned short* __restrict__ v0t) {
  __shared__ float tile[128][65];
  const int tid = threadIdx.x;
  int blk = blockIdx.x;

  if (blk < 16384) {                      // convert X (4194304 float4 exactly)
    int idx = blk * 256 + tid;
    float4 v = ((const float4*)X)[idx];
    ushort4 o;
    o.x = f2bf(v.x); o.y = f2bf(v.y); o.z = f2bf(v.z); o.w = f2bf(v.w);
    ((ushort4*)Xb)[idx] = o;
    return;
  }
  blk -= 16384;
  if (blk < 8192) {                       // convert prev_k[0] (2097152 float4)
    int idx = blk * 256 + tid;
    float4 v = ((const float4*)prevk)[idx];
    ushort4 o;
    o.x = f2bf(v.x); o.y = f2bf(v.y); o.z = f2bf(v.z); o.w = f2bf(v.w);
    ((ushort4*)k0b)[idx] = o;
    return;
  }
  blk -= 8192;

  const float* in;
  unsigned short* out;
  int N, ldo, k0, n0;
  if (blk < 1536) {                       // Wq/Wk/Wv -> WqkvT [3072][4096]
    int nt = blk % 48, kt = blk / 48;     // kt 0..31
    k0 = kt * 128;
    ldo = 4096;
    if (nt < 32)      { in = Wq; N = 2048; out = WqkvT;                         n0 = nt * 64; }
    else if (nt < 40) { in = Wk; N = 512;  out = WqkvT + (size_t)2048 * 4096;   n0 = (nt - 32) * 64; }
    else              { in = Wv; N = 512;  out = WqkvT + (size_t)2560 * 4096;   n0 = (nt - 40) * 64; }
  } else if (blk < 2048) {                // Wo (2048x2048) -> WoT
    int q = blk - 1536;
    int nt = q % 32, kt = q / 32;         // kt 0..15
    in = Wo; out = WoT; N = 2048; ldo = 2048;
    k0 = kt * 128; n0 = nt * 64;
  } else {                                // prev_v[0] slabs -> v0t [bh][64][T]
    int q = blk - 2048;
    int st = q % 16, bh = q / 16;         // st 0..15, bh 0..63
    in = prevv + (size_t)bh * T_ * HD_;
    out = v0t + (size_t)bh * HD_ * T_;
    N = 64; ldo = T_;
    k0 = st * 128; n0 = 0;
  }

  const int c = tid & 63, w = tid >> 6;
#pragma unroll
  for (int i = 0; i < 32; i++) {
    int r = w * 32 + i;
    tile[r][c] = in[(size_t)(k0 + r) * N + n0 + c];
  }
  __syncthreads();
#pragma unroll
  for (int ii = 0; ii < 16; ii++) {
    int rr = w * 16 + ii;
    unsigned int u = (unsigned int)f2bf(tile[c * 2][rr]) |
                     ((unsigned int)f2bf(tile[c * 2 + 1][rr]) << 16);
    *(unsigned int*)&out[(size_t)(n0 + rr) * ldo + k0 + c * 2] = u;
  }
}

// ---------------------------------------------------------------------------
// 128 x (NF*64) 8-phase bf16 GEMM: C(MxN fp32) = A(MxK) * Bt(NxK)^T
// (exact round-8 version -- verified)
// ---------------------------------------------------------------------------
#define SBAR  do { __builtin_amdgcn_sched_barrier(0); __builtin_amdgcn_s_barrier(); \
                   __builtin_amdgcn_sched_barrier(0); } while (0)
#define LGKM0 do { asm volatile("s_waitcnt lgkmcnt(0)" ::: "memory"); \
                   __builtin_amdgcn_sched_barrier(0); } while (0)
#define VM2   do { asm volatile("s_waitcnt vmcnt(2)" ::: "memory"); } while (0)
#define VM0   do { asm volatile("s_waitcnt vmcnt(0)" ::: "memory"); } while (0)

template <int NF>
__global__ __launch_bounds__(512, 2) void gemm128_bt(const unsigned short* __restrict__ A,
                                                     const unsigned short* __restrict__ Bt,
                                                     float* __restrict__ C,
                                                     int M, int N, int K) {
  constexpr int NHF = NF / 2;             // B frags per qn group per wave
  constexpr int BROWS = 128 + NF * 64;    // rows staged per buffer
  __shared__ __attribute__((aligned(128))) unsigned short smem[2][BROWS * 64];

  const int tid  = threadIdx.x;
  const int lane = tid & 63;
  const int wid  = tid >> 6;      // 0..7
  const int wr   = wid >> 2;      // 0..1  (M half: 64 rows)
  const int wc   = wid & 3;       // 0..3  (N quarter: NF*16 cols)
  const int la   = lane & 15;
  const int lq   = lane >> 4;
  const int sw   = la & 7;        // read-side swizzle key (row&7 == la&7)
  const int m0   = blockIdx.x * 128;
  const int n0   = blockIdx.y * (NF * 64);

  // staging: chunk = wid*2+is (1 KiB, 8 rows); lane covers physical
  // (row = chunk*8 + (lane>>3), slot = lane&7); fetches logical slot
  // (lane&7)^(row&7) so the linear DMA image realizes the XOR swizzle.
  const int sr = lane >> 3;
  const int sl = (lane & 7) ^ sr;

  const unsigned short* gA[2];
  const unsigned short* gB[NHF][2];
#pragma unroll
  for (int is = 0; is < 2; ++is) {
    int r = (wid * 2 + is) * 8 + sr;
    gA[is] = A + (size_t)(m0 + r) * K + sl * 8;
#pragma unroll
    for (int u = 0; u < NHF; ++u)
      gB[u][is] = Bt + (size_t)(n0 + u * 128 + r) * K + sl * 8;
  }

#define G_STG_A(buf, kt) do { \
    async_cp16(gA[0] + (size_t)(kt) * 64, &smem[buf][(wid * 2 + 0) * 512]); \
    async_cp16(gA[1] + (size_t)(kt) * 64, &smem[buf][(wid * 2 + 1) * 512]); \
  } while (0)
#define G_STG_B(buf, u, kt) do { \
    async_cp16(gB[u][0] + (size_t)(kt) * 64, &smem[buf][(128 + (u) * 128) * 64 + (wid * 2 + 0) * 512]); \
    async_cp16(gB[u][1] + (size_t)(kt) * 64, &smem[buf][(128 + (u) * 128) * 64 + (wid * 2 + 1) * 512]); \
  } while (0)

  f32x4  acc[4][NF] = {};
  bf16x8 aR[2][2], b0r[NHF][2], b1r[NHF][2];

#define G_RD_A(buf, qm) do { \
    const unsigned short* rp_ = &smem[buf][0]; \
    _Pragma("unroll") \
    for (int i_ = 0; i_ < 2; ++i_) { \
      int ro_ = (wr * 64 + (qm) * 32 + i_ * 16 + la) * 64; \
      aR[i_][0] = frag_ld(rp_ + ro_ + (((0 + lq) ^ sw) << 3)); \
      aR[i_][1] = frag_ld(rp_ + ro_ + (((4 + lq) ^ sw) << 3)); \
    } \
  } while (0)
#define G_RD_B(buf, qn, breg) do { \
    const unsigned short* rp_ = &smem[buf][128 * 64]; \
    _Pragma("unroll") \
    for (int j_ = 0; j_ < NHF; ++j_) { \
      int ro_ = (wc * (NF * 16) + (qn) * (NF * 8) + j_ * 16 + la) * 64; \
      breg[j_][0] = frag_ld(rp_ + ro_ + (((0 + lq) ^ sw) << 3)); \
      breg[j_][1] = frag_ld(rp_ + ro_ + (((4 + lq) ^ sw) << 3)); \
    } \
  } while (0)
#define G_MMA(qm, qn, breg) do { \
    _Pragma("unroll") \
    for (int i_ = 0; i_ < 2; ++i_) \
      _Pragma("unroll") \
      for (int j_ = 0; j_ < NHF; ++j_) { \
        f32x4 c_ = acc[(qm) * 2 + i_][(qn) * NHF + j_]; \
        c_ = mfma16(aR[i_][0], breg[j_][0], c_); \
        c_ = mfma16(aR[i_][1], breg[j_][1], c_); \
        acc[(qm) * 2 + i_][(qn) * NHF + j_] = c_; \
      } \
  } while (0)

  // prologue: tile0 fully -> buf0; tile1's prev-P8-role slot -> buf1.
  G_STG_A(0, 0);
#pragma unroll
  for (int u = 0; u < NHF; ++u) G_STG_B(0, u, 0);
  if constexpr (NF == 6) G_STG_B(1, 2, 1); else G_STG_A(1, 1);
  VM2;   // tile0's slots landed; the buf1 slot may stay in flight
  SBAR;

  const int NI = K >> 7;   // iterations of 2 K-tiles (K multiple of 128)
  for (int it = 0; it < NI; ++it) {
    const int e = it * 2;
    const bool pf = (it + 1 < NI);
    // ---- P1
    G_RD_A(0, 0);
    G_RD_B(0, 0, b0r);
    if constexpr (NF == 6) G_STG_A(1, e + 1); else G_STG_B(1, 0, e + 1);
    SBAR; LGKM0;
    __builtin_amdgcn_s_setprio(1); G_MMA(0, 0, b0r); __builtin_amdgcn_s_setprio(0);
    SBAR;
    // ---- P2
    G_RD_B(0, 1, b1r);
    if constexpr (NF == 6) G_STG_B(1, 0, e + 1); else G_STG_B(1, 1, e + 1);
    SBAR; LGKM0;
    __builtin_amdgcn_s_setprio(1); G_MMA(0, 1, b1r); __builtin_amdgcn_s_setprio(0);
    SBAR;
    // ---- P3
    G_RD_A(0, 1);
    if constexpr (NF == 6) G_STG_B(1, 1, e + 1);
    SBAR; LGKM0;
    __builtin_amdgcn_s_setprio(1); G_MMA(1, 1, b1r); __builtin_amdgcn_s_setprio(0);
    SBAR;
    // ---- P4
    if (pf) G_STG_A(0, e + 2);
    SBAR; LGKM0;
    __builtin_amdgcn_s_setprio(1); G_MMA(1, 0, b0r); __builtin_amdgcn_s_setprio(0);
    if (pf) { VM2; } else { VM0; }
    SBAR;
    // ---- P5
    G_RD_A(1, 0);
    G_RD_B(1, 0, b0r);
    if (pf) G_STG_B(0, 0, e + 2);
    SBAR; LGKM0;
    __builtin_amdgcn_s_setprio(1); G_MMA(0, 0, b0r); __builtin_amdgcn_s_setprio(0);
    SBAR;
    // ---- P6
    G_RD_B(1, 1, b1r);
    if (pf) G_STG_B(0, 1, e + 2);
    SBAR; LGKM0;
    __builtin_amdgcn_s_setprio(1); G_MMA(0, 1, b1r); __builtin_amdgcn_s_setprio(0);
    SBAR;
    // ---- P7
    G_RD_A(1, 1);
    if constexpr (NF == 6) { if (pf) G_STG_B(0, 2, e + 2); }
    SBAR; LGKM0;
    __builtin_amdgcn_s_setprio(1); G_MMA(1, 1, b1r); __builtin_amdgcn_s_setprio(0);
    SBAR;
    // ---- P8
    if constexpr (NF == 6) { if (pf) G_STG_B(1, 2, e + 3); }
    else                   { if (pf) G_STG_A(1, e + 3); }
    SBAR; LGKM0;
    __builtin_amdgcn_s_setprio(1); G_MMA(1, 0, b0r); __builtin_amdgcn_s_setprio(0);
    VM2;
    SBAR;
  }

  // epilogue: C[row, col], col = frag col + la, row = lq*4 + r within frag
#pragma unroll
  for (int mf = 0; mf < 4; ++mf) {
    int row = m0 + wr * 64 + mf * 16 + lq * 4;
#pragma unroll
    for (int nf = 0; nf < NF; ++nf) {
      int col = n0 + wc * (NF * 16) + nf * 16 + la;
#pragma unroll
      for (int r = 0; r < 4; ++r)
        C[(size_t)(row + r) * N + col] = acc[mf][nf][r];
    }
  }
#undef G_STG_A
#undef G_STG_B
#undef G_RD_A
#undef G_RD_B
#undef G_MMA
}

// ---------------------------------------------------------------------------
// RoPE: read QKV fp32, write q_b (bf16 * CSC_, [B][NH][T][D]) and knew (fp32)
__global__ __launch_bounds__(256) void rope_kernel(const float* __restrict__ QKV,
                                                   const int* __restrict__ pos_ids,
                                                   unsigned short* __restrict__ q_b,
                                                   float* __restrict__ knew) {
  int idx = blockIdx.x * 256 + threadIdx.x;
  const int total = B_ * T_ * (NH_ + NKV_) * 32;
  if (idx >= total) return;
  int i = idx & 31;
  int tmp = idx >> 5;
  int hh = tmp % (NH_ + NKV_);
  int bt = tmp / (NH_ + NKV_);
  int t = bt & (T_ - 1);
  int b = bt >> 11;
  int pos = pos_ids[bt] + STEPS_;
  float inv = exp2f(-(float)i * (13.287712379549449f / 32.0f));
  float ang = (float)pos * inv;
  float sn, cs;
  sincosf(ang, &sn, &cs);
  const float* rowp = QKV + (size_t)bt * 3072;
  if (hh < NH_) {
    float x1 = rowp[hh * 64 + i];
    float x2 = rowp[hh * 64 + 32 + i];
    float y1 = (x1 * cs - x2 * sn) * CSC_;   // fold score scale into q
    float y2 = (x2 * cs + x1 * sn) * CSC_;
    size_t o = ((size_t)(b * NH_ + hh) * T_ + t) * HD_ + i;
    q_b[o] = f2bf(y1);
    q_b[o + 32] = f2bf(y2);
  } else {
    int kv = hh - NH_;
    float x1 = rowp[2048 + kv * 64 + i];
    float x2 = rowp[2048 + kv * 64 + 32 + i];
    float y1 = x1 * cs - x2 * sn;
    float y2 = x2 * cs + x1 * sn;
    size_t o = ((size_t)(b * NKV_ + kv) * T_ + t) * HD_ + i;
    knew[o] = y1;
    knew[o + 32] = y2;
  }
}

// ---------------------------------------------------------------------------
// Flash attention v2, swapped-QK^T, fused epilogue, low-latency softmax.
// (exact round-8 version -- verified)
__global__ __launch_bounds__(256, 3) void flash_kernel(const unsigned short* __restrict__ qb,
                                                       const unsigned short* __restrict__ k0b,
                                                       const unsigned short* __restrict__ v0t,
                                                       const float* __restrict__ prev_k,
                                                       const float* __restrict__ prev_v,
                                                       const float* __restrict__ knew,
                                                       const float* __restrict__ QKV,
                                                       unsigned short* __restrict__ attnout) {
  __shared__ unsigned short sK[2][64 * 64];
  __shared__ unsigned short sV[2][64 * 64];
  __shared__ unsigned short sP[4][2][16 * 72];

  const int tid = threadIdx.x;
  const int lane = tid & 63;
  const int wave = tid >> 6;
  const int la = lane & 15;
  const int lq = lane >> 4;
  const int swz = la & 7;

  const int id = blockIdx.x;
  const int bh = (id & 7) * 8 + ((id >> 3) & 7);
  const int qt = 15 - (id >> 6);

  const size_t bhs = (size_t)bh;
  const unsigned short* gK = k0b + bhs * T_ * HD_;
  const unsigned short* gV = v0t + bhs * HD_ * T_;

  const int rb0 = qt * 128 + wave * 32;
  const int ktd = rb0 >> 6;
  const int ktmax = 2 * qt + 1;

  bf16x8 aq[2][2];
#pragma unroll
  for (int f = 0; f < 2; f++) {
    const unsigned short* qp = qb + (bhs * T_ + rb0 + f * 16 + la) * HD_;
    aq[f][0] = frag_ld(qp + lq * 8);
    aq[f][1] = frag_ld(qp + 32 + lq * 8);
  }

  f32x4 o[2][4] = {};
  float m_f[2] = {-1e30f, -1e30f};
  float l_p[2] = {0.0f, 0.0f};   // per-lane partial row-sum (lq-slice)

  const int lrow = lane >> 3;
  const int lcb = (lane & 7) ^ lrow;

  {
    unsigned short* kd = &sK[0][wave * 1024];
    unsigned short* vd = &sV[0][wave * 1024];
    async_cp16(gK + (size_t)(wave * 16 + lrow) * HD_ + lcb * 8, kd);
    async_cp16(gK + (size_t)(wave * 16 + 8 + lrow) * HD_ + lcb * 8, kd + 512);
    async_cp16(gV + (size_t)(wave * 16 + lrow) * T_ + lcb * 8, vd);
    async_cp16(gV + (size_t)(wave * 16 + 8 + lrow) * T_ + lcb * 8, vd + 512);
  }
  __syncthreads();

  int cur = 0;
  for (int kt = 0; kt <= ktmax; ++kt) {
    if (kt < ktmax) {
      const int nk = (kt + 1) * 64;
      unsigned short* kd = &sK[cur ^ 1][wave * 1024];
      unsigned short* vd = &sV[cur ^ 1][wave * 1024];
      async_cp16(gK + (size_t)(nk + wave * 16 + lrow) * HD_ + lcb * 8, kd);
      async_cp16(gK + (size_t)(nk + wave * 16 + 8 + lrow) * HD_ + lcb * 8, kd + 512);
      async_cp16(gV + (size_t)(wave * 16 + lrow) * T_ + nk + lcb * 8, vd);
      async_cp16(gV + (size_t)(wave * 16 + 8 + lrow) * T_ + nk + lcb * 8, vd + 512);
    }

    if (kt <= ktd) {
      const unsigned short* kb = &sK[cur][0];
      const unsigned short* vb = &sV[cur][0];

      bf16x8 bk0[4], bk1[4];
#pragma unroll
      for (int nb = 0; nb < 4; nb++) {
        const unsigned short* rp = kb + (nb * 16 + la) * 64;
        bk0[nb] = frag_ld(rp + ((lq ^ swz) << 3));
        bk1[nb] = frag_ld(rp + (((lq + 4) ^ swz) << 3));
      }
      // S^T = K * Q^T : lane la = q-row (frag f), key = nb*16 + lq*4 + r
      f32x4 s[2][4];
      __builtin_amdgcn_s_setprio(1);
#pragma unroll
      for (int f = 0; f < 2; f++)
#pragma unroll
        for (int nb = 0; nb < 4; nb++) {
          f32x4 z = {0.f, 0.f, 0.f, 0.f};
          z = mfma16(bk0[nb], aq[f][0], z);
          z = mfma16(bk1[nb], aq[f][1], z);
          s[f][nb] = z;
        }
      __builtin_amdgcn_s_setprio(0);

      // V fragment reads issued early: DS latency hides under softmax VALU
      bf16x8 bv0[4], bv1[4];
#pragma unroll
      for (int jd = 0; jd < 4; jd++) {
        const unsigned short* rp = vb + (jd * 16 + la) * 64;
        bv0[jd] = frag_ld(rp + ((lq ^ swz) << 3));
        bv1[jd] = frag_ld(rp + (((lq + 4) ^ swz) << 3));
      }

      const bool diag = (kt == ktd);
#pragma unroll
      for (int f = 0; f < 2; f++) {
        const int qrow = rb0 + f * 16 + la;
        if (diag) {
#pragma unroll
          for (int nb = 0; nb < 4; nb++)
#pragma unroll
            for (int r = 0; r < 4; r++) {
              int key = kt * 64 + nb * 16 + lq * 4 + r;
              s[f][nb][r] = (key <= qrow) ? s[f][nb][r] : -1e30f;
            }
        }
        // per-lane max over this lane's 16 keys (no cross-lane in common path)
        float t0 = fmaxf(fmaxf(s[f][0][0], s[f][0][1]), fmaxf(s[f][0][2], s[f][0][3]));
        float t1 = fmaxf(fmaxf(s[f][1][0], s[f][1][1]), fmaxf(s[f][1][2], s[f][1][3]));
        float t2 = fmaxf(fmaxf(s[f][2][0], s[f][2][1]), fmaxf(s[f][2][2], s[f][2][3]));
        float t3 = fmaxf(fmaxf(s[f][3][0], s[f][3][1]), fmaxf(s[f][3][2], s[f][3][3]));
        float tm = fmaxf(fmaxf(t0, t1), fmaxf(t2, t3));
        // defer-max (T13): rescale only if some lane's slice-max passed m+8
        const bool resc = __any(tm > m_f[f] + 8.0f);
        if (resc) {
          tm = fmaxf(tm, __shfl_xor(tm, 16));
          tm = fmaxf(tm, __shfl_xor(tm, 32));
          float mn = fmaxf(m_f[f], tm);
          float al = exp2f(m_f[f] - mn);   // row-uniform across lq
          m_f[f] = mn;
          l_p[f] *= al;
          // al lives on lane (la = qrow); O accumulator has qrow = lq*4+r
          float a0 = __shfl(al, lq * 4 + 0);
          float a1 = __shfl(al, lq * 4 + 1);
          float a2 = __shfl(al, lq * 4 + 2);
          float a3 = __shfl(al, lq * 4 + 3);
#pragma unroll
          for (int jd = 0; jd < 4; jd++) {
            o[f][jd][0] *= a0;
            o[f][jd][1] *= a1;
            o[f][jd][2] *= a2;
            o[f][jd][3] *= a3;
          }
        }
        float ls = 0.0f;
#pragma unroll
        for (int nb = 0; nb < 4; nb++)
#pragma unroll
          for (int r = 0; r < 4; r++) {
            float p = exp2f(s[f][nb][r] - m_f[f]);
            s[f][nb][r] = p;
            ls += p;
          }
        l_p[f] += ls;   // per-lane partial; lq-reduction deferred to tail
        // write this f's P into its own sP half (both halves live at once)
        unsigned short* pw = &sP[wave][f][0];
#pragma unroll
        for (int nb = 0; nb < 4; nb++) {
          unsigned int p01 = cvtpk_bf16(s[f][nb][0], s[f][nb][1]);
          unsigned int p23 = cvtpk_bf16(s[f][nb][2], s[f][nb][3]);
          unsigned long long pq = ((unsigned long long)p23 << 32) | (unsigned long long)p01;
          *(unsigned long long*)(pw + la * 72 + nb * 16 + lq * 4) = pq;
        }
      }

      // PV: one LDS round-trip wait covers both f halves
#pragma unroll
      for (int f = 0; f < 2; f++) {
        const unsigned short* pr = &sP[wave][f][0];
        bf16x8 ap0 = frag_ld(&pr[la * 72 + lq * 8]);
        bf16x8 ap1 = frag_ld(&pr[la * 72 + 32 + lq * 8]);
        __builtin_amdgcn_s_setprio(1);
#pragma unroll
        for (int jd = 0; jd < 4; jd++) {
          o[f][jd] = mfma16(ap0, bv0[jd], o[f][jd]);
          o[f][jd] = mfma16(ap1, bv1[jd], o[f][jd]);
        }
        __builtin_amdgcn_s_setprio(0);
      }
    }
    __syncthreads();
    cur ^= 1;
  }

  // finalize l: reduce the per-lane partials over the lq axis (once)
#pragma unroll
  for (int f = 0; f < 2; f++) {
    l_p[f] += __shfl_xor(l_p[f], 16);
    l_p[f] += __shfl_xor(l_p[f], 32);
  }

  // ---- fused epilogue: fold diagonal keys (prev_k[1], new k) and write bf16
  const int bI = bh >> 5;
  const int hI = bh & 31;
  const int kvI = hI >> 2;
  const size_t P1 = (size_t)B_ * NH_ * T_ * HD_;
  const float* k1base = prev_k + P1 + bhs * T_ * HD_;
  const float* v1base = prev_v + P1 + bhs * T_ * HD_;
  const float* knbase = knew + ((size_t)bI * NKV_ + kvI) * T_ * HD_;
  const float* vnbase = QKV + (size_t)bI * T_ * 3072 + 2560 + kvI * 64;
  unsigned short* aobase = attnout + (size_t)bI * T_ * (NH_ * HD_) + hI * HD_;

#pragma unroll
  for (int f = 0; f < 2; f++) {
    const int rowA = rb0 + f * 16 + la;   // dot-domain row (la), all lq share
    const float* k1p = k1base + (size_t)rowA * HD_;
    const float* knp = knbase + (size_t)rowA * HD_;
    float e1 = 0.f, e2 = 0.f;
#pragma unroll
    for (int h2 = 0; h2 < 2; h2++) {
      const int dd = h2 * 32 + lq * 8;
#pragma unroll
      for (int j = 0; j < 8; j++) {
        float qv = (float)aq[f][h2][j];   // bf16 q incl CSC_ (== old q_b read)
        e1 = fmaf(qv, k1p[dd + j], e1);
        e2 = fmaf(qv, knp[dd + j], e2);
      }
    }
    e1 += __shfl_xor(e1, 16); e1 += __shfl_xor(e1, 32);
    e2 += __shfl_xor(e2, 16); e2 += __shfl_xor(e2, 32);
    float mx = fmaxf(m_f[f], fmaxf(e1, e2));
    float w0 = exp2f(m_f[f] - mx);
    float w1 = exp2f(e1 - mx);
    float w2 = exp2f(e2 - mx);
    float inv = 1.0f / (l_p[f] * w0 + w1 + w2);
    float s0 = w0 * inv, s1 = w1 * inv, s2 = w2 * inv;
    // move per-row scalars (on lanes 0..15) to the O domain (row = lq*4+r)
    float a0[4], a1[4], a2[4];
#pragma unroll
    for (int r = 0; r < 4; r++) {
      a0[r] = __shfl(s0, lq * 4 + r);
      a1[r] = __shfl(s1, lq * 4 + r);
      a2[r] = __shfl(s2, lq * 4 + r);
    }
#pragma unroll
    for (int r = 0; r < 4; r++) {
      const int rowO = rb0 + f * 16 + lq * 4 + r;
      const float* v1p = v1base + (size_t)rowO * HD_;
      const float* vnp = vnbase + (size_t)rowO * 3072;
      unsigned short* aop = aobase + (size_t)rowO * (NH_ * HD_);
#pragma unroll
      for (int jd = 0; jd < 4; jd++) {
        int d = jd * 16 + la;
        float out = o[f][jd][r] * a0[r] + v1p[d] * a1[r] + vnp[d] * a2[r];
        aop[d] = f2bf(out);
      }
    }
  }
}

// ---------------------------------------------------------------------------
// Workspace layout (bytes; needs ws_size >= 178,257,920)
#define OFF_QKV   ((size_t)0)
#define OFF_XB    ((size_t)50331648)
#define OFF_WQKVT ((size_t)83886080)
#define OFF_WOT   ((size_t)109051904)
#define OFF_QB    ((size_t)117440512)
#define OFF_K0B   ((size_t)134217728)
#define OFF_V0T   ((size_t)150994944)
#define OFF_KNEW  ((size_t)167772160)
#define OFF_ML    ((size_t)176160768)

extern "C" void kernel_launch(void* const* d_in, const int* in_sizes, int n_in,
                              void* d_out, int out_size, void* d_ws, size_t ws_size,
                              hipStream_t stream) {
  const float* X = (const float*)d_in[0];
  const int* pos = (const int*)d_in[2];
  const float* prevk = (const float*)d_in[3];
  const float* prevv = (const float*)d_in[4];
  const float* Wq = (const float*)d_in[5];
  const float* Wk = (const float*)d_in[6];
  const float* Wv = (const float*)d_in[7];
  const float* Wo = (const float*)d_in[8];

  char* ws = (char*)d_ws;
  float* QKV = (float*)(ws + OFF_QKV);
  unsigned short* Xb = (unsigned short*)(ws + OFF_XB);
  unsigned short* WqkvT = (unsigned short*)(ws + OFF_WQKVT);
  unsigned short* attnout = (unsigned short*)(ws + OFF_WQKVT);
  unsigned short* WoT = (unsigned short*)(ws + OFF_WOT);
  unsigned short* q_b = (unsigned short*)(ws + OFF_QB);
  unsigned short* k0b = (unsigned short*)(ws + OFF_K0B);
  unsigned short* v0t = (unsigned short*)(ws + OFF_V0T);
  float* knew = (float*)(ws + OFF_KNEW);

  // merged preprocessing: converts + all transposes, one dispatch
  preproc<<<27648, 256, 0, stream>>>(X, prevk, prevv, Wq, Wk, Wv, Wo,
                                     Xb, k0b, WqkvT, WoT, v0t);

  // QKV GEMM: M=4096, N=3072, K=4096; BM=128, BN=384 -> grid 32x8 = 256
  gemm128_bt<6><<<dim3(32, 8), 512, 0, stream>>>(Xb, WqkvT, QKV, 4096, 3072, 4096);

  rope_kernel<<<20480, 256, 0, stream>>>(QKV, pos, q_b, knew);

  // flash with fused diagonal-key epilogue -> writes attnout bf16 directly
  flash_kernel<<<1024, 256, 0, stream>>>(q_b, k0b, v0t, prevk, prevv, knew, QKV, attnout);

  // Wo GEMM: M=4096, N=2048, K=2048; BM=128, BN=256 -> grid 32x8 = 256
  gemm128_bt<4><<<dim3(32, 8), 512, 0, stream>>>(attnout, WoT, (float*)d_out, 4096, 2048, 2048);
}